// Round 1
// baseline (238.898 us; speedup 1.0000x reference)
//
#include <hip/hip_runtime.h>
#include <hip/hip_bf16.h>
#include <math.h>

#define N_NODES 10000
#define N_EDGES 160000
#define B_ 8
#define D_ 64
#define BD 512          // B_*D_
#define ROWS 80000      // N_NODES*B_

// ---------------- CSR build ----------------

__global__ void zero_counts_kernel(int* __restrict__ counts) {
    int i = blockIdx.x * blockDim.x + threadIdx.x;
    if (i < N_NODES) counts[i] = 0;
}

__global__ void hist_kernel(const int* __restrict__ dst, int* __restrict__ counts) {
    int e = blockIdx.x * blockDim.x + threadIdx.x;
    if (e < N_EDGES) atomicAdd(&counts[dst[e]], 1);
}

// single block, 256 threads, 40 elements/thread (10240 >= 10000)
__global__ void scan_kernel(const int* __restrict__ counts,
                            int* __restrict__ offsets, int* __restrict__ cursor) {
    __shared__ int sums[256];
    int t = threadIdx.x;
    int base = t * 40;
    int local[40];
    int s = 0;
#pragma unroll
    for (int i = 0; i < 40; i++) {
        int idx = base + i;
        int v = (idx < N_NODES) ? counts[idx] : 0;
        local[i] = s;
        s += v;
    }
    sums[t] = s;
    __syncthreads();
    for (int off = 1; off < 256; off <<= 1) {
        int v = (t >= off) ? sums[t - off] : 0;
        __syncthreads();
        sums[t] += v;
        __syncthreads();
    }
    int ex = (t == 0) ? 0 : sums[t - 1];
#pragma unroll
    for (int i = 0; i < 40; i++) {
        int idx = base + i;
        if (idx < N_NODES) {
            int o = ex + local[i];
            offsets[idx] = o;
            cursor[idx] = o;
        }
    }
    if (t == 255) offsets[N_NODES] = sums[255];
}

__global__ void scatter_kernel(const int* __restrict__ src, const int* __restrict__ dst,
                               const float* __restrict__ dist,
                               int* __restrict__ cursor,
                               int* __restrict__ src_sorted, float* __restrict__ dist_sorted) {
    int e = blockIdx.x * blockDim.x + threadIdx.x;
    if (e < N_EDGES) {
        int d = dst[e];
        int pos = atomicAdd(&cursor[d], 1);
        src_sorted[pos] = src[e];
        dist_sorted[pos] = dist[e];
    }
}

// ---------------- node projection: P_src = state @ W[0:64], P_dst = state @ W[64:128] ----------------
// state viewed as [ROWS, 64]; W is [128, 64] row-major. Output col c in [0,128):
// P[row][c] = sum_k state[row][k] * W[(c>=64?64:0)+k][c&63]
// Block: 256 threads handles 64 rows; thread (rt=t>>4, ct=t&15) computes 4 rows x 8 cols.
__global__ void __launch_bounds__(256) proj_kernel(const float* __restrict__ state,
                                                   const float* __restrict__ weight,
                                                   float* __restrict__ P_src,
                                                   float* __restrict__ P_dst) {
    __shared__ float Wl[64 * 128];   // Wl[k*128 + c] = weight[(h*64+k)*64 + d], c=h*64+d
    __shared__ float rows[64 * 65];  // padded leading dim 65
    int t = threadIdx.x;
    for (int i = t; i < 8192; i += 256) {
        int k = i >> 7;
        int c = i & 127;
        int h = c >> 6, d = c & 63;
        Wl[i] = weight[(h * 64 + k) * 64 + d];
    }
    int row0 = blockIdx.x * 64;
    for (int i = t; i < 4096; i += 256) {
        int r = i >> 6, k = i & 63;
        rows[r * 65 + k] = state[(row0 + r) * 64 + k];
    }
    __syncthreads();

    int ct = t & 15;   // cols ct*8 .. ct*8+7
    int rt = t >> 4;   // rows rt*4 .. rt*4+3
    float acc[4][8];
#pragma unroll
    for (int i = 0; i < 4; i++)
#pragma unroll
        for (int j = 0; j < 8; j++) acc[i][j] = 0.f;

    const float4* Wl4 = (const float4*)Wl;
#pragma unroll 4
    for (int k = 0; k < 64; k++) {
        float4 b0 = Wl4[k * 32 + ct * 2];
        float4 b1 = Wl4[k * 32 + ct * 2 + 1];
        float b[8] = {b0.x, b0.y, b0.z, b0.w, b1.x, b1.y, b1.z, b1.w};
        float a[4];
#pragma unroll
        for (int i = 0; i < 4; i++) a[i] = rows[(rt * 4 + i) * 65 + k];
#pragma unroll
        for (int i = 0; i < 4; i++)
#pragma unroll
            for (int j = 0; j < 8; j++) acc[i][j] = fmaf(a[i], b[j], acc[i][j]);
    }

#pragma unroll
    for (int i = 0; i < 4; i++) {
        int row = row0 + rt * 4 + i;
        float4 v0 = make_float4(acc[i][0], acc[i][1], acc[i][2], acc[i][3]);
        float4 v1 = make_float4(acc[i][4], acc[i][5], acc[i][6], acc[i][7]);
        if (ct < 8) {
            float4* p = (float4*)(P_src + row * 64 + ct * 8);
            p[0] = v0; p[1] = v1;
        } else {
            float4* p = (float4*)(P_dst + row * 64 + (ct - 8) * 8);
            p[0] = v0; p[1] = v1;
        }
    }
}

// ---------------- fused online segment-softmax + aggregate ----------------
// One block (512 threads = B*D) per dst node; single pass over incoming edges.
__global__ void __launch_bounds__(512) gat_aggregate(
    const float* __restrict__ state, const float* __restrict__ P_src,
    const float* __restrict__ P_dst, const int* __restrict__ offsets,
    const int* __restrict__ src_sorted, const float* __restrict__ dist_sorted,
    float* __restrict__ out) {
    int n = blockIdx.x;
    int t = threadIdx.x;  // t = b*64 + d
    float p_dst = P_dst[n * BD + t];
    int off = offsets[n];
    int end = offsets[n + 1];
    float m = -INFINITY, l = 0.f, o = 0.f;
    for (int j = off; j < end; j++) {
        int s = src_sorted[j];
        float dist = dist_sorted[j];
        float z = P_src[s * BD + t] + p_dst;
        float a = (z > 0.f ? z : 0.2f * z) * dist;   // leaky_relu(0.2) * dist
        float x = state[s * BD + t];
        float mn = fmaxf(m, a);
        float e1 = __expf(m - mn);
        float e2 = __expf(a - mn);
        l = l * e1 + e2;
        o = o * e1 + e2 * x;
        m = mn;
    }
    float r = (end > off) ? fmaxf(o / l, 0.f) : 0.f;
    out[n * BD + t] = r;
}

extern "C" void kernel_launch(void* const* d_in, const int* in_sizes, int n_in,
                              void* d_out, int out_size, void* d_ws, size_t ws_size,
                              hipStream_t stream) {
    const float* state  = (const float*)d_in[0];
    // d_in[1] = feature (unused by the math)
    const float* weight = (const float*)d_in[2];
    const int*   src    = (const int*)d_in[3];
    const int*   dst    = (const int*)d_in[4];
    const float* dist   = (const float*)d_in[5];
    float* out = (float*)d_out;

    // workspace layout (all 4B types; P arrays 16B aligned)
    float* P_src       = (float*)d_ws;                 // N*B*D = 5,120,000
    float* P_dst       = P_src + (size_t)N_NODES * BD; // 5,120,000
    float* dist_sorted = P_dst + (size_t)N_NODES * BD; // E
    int*   src_sorted  = (int*)(dist_sorted + N_EDGES);// E
    int*   counts      = src_sorted + N_EDGES;         // N
    int*   offsets     = counts + N_NODES;             // N+1
    int*   cursor      = offsets + N_NODES + 1;        // N

    zero_counts_kernel<<<(N_NODES + 255) / 256, 256, 0, stream>>>(counts);
    hist_kernel<<<(N_EDGES + 255) / 256, 256, 0, stream>>>(dst, counts);
    scan_kernel<<<1, 256, 0, stream>>>(counts, offsets, cursor);
    scatter_kernel<<<(N_EDGES + 255) / 256, 256, 0, stream>>>(src, dst, dist, cursor,
                                                              src_sorted, dist_sorted);
    proj_kernel<<<ROWS / 64, 256, 0, stream>>>(state, weight, P_src, P_dst);
    gat_aggregate<<<N_NODES, BD, 0, stream>>>(state, P_src, P_dst, offsets,
                                              src_sorted, dist_sorted, out);
}

// Round 2
// 191.743 us; speedup vs baseline: 1.2459x; 1.2459x over previous
//
#include <hip/hip_runtime.h>
#include <hip/hip_fp16.h>
#include <math.h>

#define N_NODES 10000
#define N_EDGES 160000
#define B_ 8
#define D_ 64
#define BD 512          // B_*D_
#define ROWS 80000      // N_NODES*B_

// ---------------- CSR build ----------------

__global__ void zero_counts_kernel(int* __restrict__ counts) {
    int i = blockIdx.x * blockDim.x + threadIdx.x;
    if (i < N_NODES) counts[i] = 0;
}

__global__ void hist_kernel(const int* __restrict__ dst, int* __restrict__ counts) {
    int e = blockIdx.x * blockDim.x + threadIdx.x;
    if (e < N_EDGES) atomicAdd(&counts[dst[e]], 1);
}

// single block, 256 threads; counts staged through LDS for coalesced global reads
__global__ void scan_kernel(const int* __restrict__ counts,
                            int* __restrict__ offsets, int* __restrict__ cursor) {
    __shared__ int c_lds[10240];
    __shared__ int sums[256];
    int t = threadIdx.x;
    for (int i = t; i < 10240; i += 256) c_lds[i] = (i < N_NODES) ? counts[i] : 0;
    __syncthreads();
    int base = t * 40;
    int local[40];
    int s = 0;
#pragma unroll
    for (int i = 0; i < 40; i++) {
        local[i] = s;
        s += c_lds[base + i];
    }
    sums[t] = s;
    __syncthreads();
    for (int off = 1; off < 256; off <<= 1) {
        int v = (t >= off) ? sums[t - off] : 0;
        __syncthreads();
        sums[t] += v;
        __syncthreads();
    }
    int ex = (t == 0) ? 0 : sums[t - 1];
#pragma unroll
    for (int i = 0; i < 40; i++) {
        int idx = base + i;
        if (idx < N_NODES) {
            int o = ex + local[i];
            offsets[idx] = o;
            cursor[idx] = o;
        }
    }
    if (t == 255) offsets[N_NODES] = sums[255];
}

__global__ void scatter_kernel(const int* __restrict__ src, const int* __restrict__ dst,
                               const float* __restrict__ dist,
                               int* __restrict__ cursor,
                               int* __restrict__ src_sorted, float* __restrict__ dist_sorted) {
    int e = blockIdx.x * blockDim.x + threadIdx.x;
    if (e < N_EDGES) {
        int d = dst[e];
        int pos = atomicAdd(&cursor[d], 1);
        src_sorted[pos] = src[e];
        dist_sorted[pos] = dist[e];
    }
}

// ---------------- node projection ----------------
// state viewed as [ROWS,64]; W is [128,64] row-major (rows 0..63 = src part, 64..127 = dst part).
// Outputs:
//   G[row*64 + d]  = half2{ P_src[row][d], state[row][d] }   (the per-edge gather payload)
//   Pd[row*64 + d] = half( P_dst[row][d] )
// Block: 256 threads, 64 rows. Thread (rt=t>>4, ct=t&15): 4 rows x (4 src cols + 4 dst cols).
// b-loads are float4 at stride-4-cols => 2-way LDS bank aliasing only (free on gfx950).
__global__ void __launch_bounds__(256) proj_kernel(const float* __restrict__ state,
                                                   const float* __restrict__ weight,
                                                   __half2* __restrict__ G,
                                                   __half* __restrict__ Pd) {
    __shared__ float Wl[64 * 128];   // Wl[k*128 + c]; c<64: W[k][c], c>=64: W[64+k][c-64]
    __shared__ float rows[64 * 68];  // padded leading dim 68 (float4-aligned)
    int t = threadIdx.x;
    for (int i = t; i < 8192; i += 256) {
        int k = i >> 7;
        int c = i & 127;
        int h = c >> 6, d = c & 63;
        Wl[i] = weight[(h * 64 + k) * 64 + d];
    }
    int row0 = blockIdx.x * 64;
    const float4* st4 = (const float4*)(state + (size_t)row0 * 64);
    for (int i = t; i < 1024; i += 256) {
        int r = i >> 4, kq = i & 15;
        *(float4*)&rows[r * 68 + kq * 4] = st4[i];
    }
    __syncthreads();

    int ct = t & 15;
    int rt = t >> 4;
    float acc[4][8];
#pragma unroll
    for (int i = 0; i < 4; i++)
#pragma unroll
        for (int j = 0; j < 8; j++) acc[i][j] = 0.f;

    const float4* Wl4 = (const float4*)Wl;
    for (int k4 = 0; k4 < 64; k4 += 4) {
        float4 a4[4];
#pragma unroll
        for (int i = 0; i < 4; i++) a4[i] = *(const float4*)&rows[(rt * 4 + i) * 68 + k4];
#pragma unroll
        for (int kk = 0; kk < 4; kk++) {
            int k = k4 + kk;
            float4 bs = Wl4[k * 32 + ct];        // src cols ct*4..+3
            float4 bd = Wl4[k * 32 + 16 + ct];   // dst cols 64+ct*4..+3
            float bv[8] = {bs.x, bs.y, bs.z, bs.w, bd.x, bd.y, bd.z, bd.w};
#pragma unroll
            for (int i = 0; i < 4; i++) {
                float a = ((const float*)&a4[i])[kk];
#pragma unroll
                for (int jj = 0; jj < 8; jj++) acc[i][jj] = fmaf(a, bv[jj], acc[i][jj]);
            }
        }
    }

#pragma unroll
    for (int i = 0; i < 4; i++) {
        int rloc = rt * 4 + i;
        size_t row = row0 + rloc;
        union { float4 f; __half2 h[4]; } gu;
#pragma unroll
        for (int jj = 0; jj < 4; jj++) {
            float x = rows[rloc * 68 + ct * 4 + jj];
            gu.h[jj] = __floats2half2_rn(acc[i][jj], x);   // low = p_src, high = state
        }
        *(float4*)&G[row * 64 + ct * 4] = gu.f;
        union { float2 f; __half h[4]; } du;
#pragma unroll
        for (int jj = 0; jj < 4; jj++) du.h[jj] = __float2half_rn(acc[i][4 + jj]);
        *(float2*)&Pd[row * 64 + ct * 4] = du.f;
    }
}

// ---------------- fused segment-softmax + aggregate ----------------
// alpha = leaky_relu(z)*dist is bounded (|z| small, dist in [0,1]) => no max-subtraction
// needed for fp32 exp. One block of 128 threads per dst node; each thread owns 4
// contiguous (b,d) elements => one 16B gather per edge per lane.
__global__ void __launch_bounds__(128) gat_aggregate(
    const float4* __restrict__ G4,      // [N*128], each = 4 x half2{p_src, state}
    const float2* __restrict__ Pd2,     // [N*128], each = 4 x half (P_dst)
    const int* __restrict__ offsets,
    const int* __restrict__ src_sorted,
    const float* __restrict__ dist_sorted,
    float4* __restrict__ out4) {
    int n = blockIdx.x;
    int t = threadIdx.x;  // element group: e = 4t .. 4t+3 of 512

    union { float2 f; __half2 h[2]; } pu;
    pu.f = Pd2[(size_t)n * 128 + t];
    float pd[4] = {__low2float(pu.h[0]), __high2float(pu.h[0]),
                   __low2float(pu.h[1]), __high2float(pu.h[1])};

    int off = offsets[n];
    int end = offsets[n + 1];
    float l[4] = {0.f, 0.f, 0.f, 0.f};
    float o[4] = {0.f, 0.f, 0.f, 0.f};

    int j = off;
    if (j < end) {
        int s = src_sorted[j];
        float dd = dist_sorted[j];
        float4 g = G4[(size_t)s * 128 + t];
        for (;;) {
            // prefetch next edge while processing current
            int jn = j + 1;
            bool more = jn < end;
            int s2 = s; float dd2 = dd; float4 g2 = g;
            if (more) {
                s2 = src_sorted[jn];
                dd2 = dist_sorted[jn];
                g2 = G4[(size_t)s2 * 128 + t];
            }
            union { float4 f; __half2 h[4]; } gu;
            gu.f = g;
#pragma unroll
            for (int e = 0; e < 4; e++) {
                float p = __low2float(gu.h[e]);
                float x = __high2float(gu.h[e]);
                float z = p + pd[e];
                float a = (z > 0.f ? z : 0.2f * z) * dd;
                float ex = __expf(a);
                l[e] += ex;
                o[e] = fmaf(ex, x, o[e]);
            }
            if (!more) break;
            j = jn; s = s2; dd = dd2; g = g2;
        }
    }

    float4 r;
    bool nz = end > off;
    r.x = nz ? fmaxf(o[0] / l[0], 0.f) : 0.f;
    r.y = nz ? fmaxf(o[1] / l[1], 0.f) : 0.f;
    r.z = nz ? fmaxf(o[2] / l[2], 0.f) : 0.f;
    r.w = nz ? fmaxf(o[3] / l[3], 0.f) : 0.f;
    out4[(size_t)n * 128 + t] = r;
}

extern "C" void kernel_launch(void* const* d_in, const int* in_sizes, int n_in,
                              void* d_out, int out_size, void* d_ws, size_t ws_size,
                              hipStream_t stream) {
    const float* state  = (const float*)d_in[0];
    // d_in[1] = feature (unused by the math)
    const float* weight = (const float*)d_in[2];
    const int*   src    = (const int*)d_in[3];
    const int*   dst    = (const int*)d_in[4];
    const float* dist   = (const float*)d_in[5];

    // workspace layout (16B-aligned head first)
    __half2* G          = (__half2*)d_ws;                      // ROWS*64 half2 = 20.48 MB
    __half*  Pd         = (__half*)(G + (size_t)ROWS * 64);    // ROWS*64 half  = 10.24 MB
    float*   dist_sorted= (float*)(Pd + (size_t)ROWS * 64);    // E
    int*     src_sorted = (int*)(dist_sorted + N_EDGES);       // E
    int*     counts     = src_sorted + N_EDGES;                // N
    int*     offsets    = counts + N_NODES;                    // N+1
    int*     cursor     = offsets + N_NODES + 1;               // N

    zero_counts_kernel<<<(N_NODES + 255) / 256, 256, 0, stream>>>(counts);
    hist_kernel<<<(N_EDGES + 255) / 256, 256, 0, stream>>>(dst, counts);
    scan_kernel<<<1, 256, 0, stream>>>(counts, offsets, cursor);
    scatter_kernel<<<(N_EDGES + 255) / 256, 256, 0, stream>>>(src, dst, dist, cursor,
                                                              src_sorted, dist_sorted);
    proj_kernel<<<ROWS / 64, 256, 0, stream>>>(state, weight, G, Pd);
    gat_aggregate<<<N_NODES, 128, 0, stream>>>((const float4*)G, (const float2*)Pd,
                                               offsets, src_sorted, dist_sorted,
                                               (float4*)d_out);
}